// Round 1
// baseline (782.030 us; speedup 1.0000x reference)
//
#include <hip/hip_runtime.h>

#define TT 1024
#define NN 256
#define CC 128
#define SS 128
#define NEG (-1e30f)
#define LOG2E 1.4426950408889634f
#define LN2 0.6931471805599453f

// log-sum-exp in log2 domain, 2-arg: log2(2^a + 2^b)
__device__ __forceinline__ float lae2(float a, float b) {
    float m = fmaxf(a, b);
    float mn = fminf(a, b);
    float s = 1.0f + __builtin_amdgcn_exp2f(mn - m);
    return m + __builtin_amdgcn_logf(s);   // v_log_f32 is log2
}
// 3-arg: log2(2^a + 2^b + 2^c)
__device__ __forceinline__ float lae3(float a, float b, float c) {
    float m = fmaxf(fmaxf(a, b), c);       // fuses to v_max3_f32
    float s = __builtin_amdgcn_exp2f(a - m) + __builtin_amdgcn_exp2f(b - m)
            + __builtin_amdgcn_exp2f(c - m);
    return m + __builtin_amdgcn_logf(s);
}

// One wave (64 lanes) per batch sample. Lane i owns extended positions
// l = 4i .. 4i+3 (a0..a3); lane 63 additionally owns l=256 (a4).
// Cross-lane dep per step: only alpha[4i-1] = prev lane's a3 (one shfl_up).
__global__ __launch_bounds__(64, 1) void ctc_alpha_kernel(
    const float* __restrict__ lp, const int* __restrict__ tgt,
    const int* __restrict__ ilen_p, const int* __restrict__ tlen_p,
    float* __restrict__ ws)
{
    const int n = blockIdx.x;
    const int lane = threadIdx.x;
    const int ilen = ilen_p[n];
    const int tlen = tlen_p[n];

    // time-invariant gather indices: ext[4i+1]=tgt[2i], ext[4i+3]=tgt[2i+1]
    const int te = tgt[n * SS + 2 * lane]     & (CC - 1);
    const int to = tgt[n * SS + 2 * lane + 1] & (CC - 1);
    const int tprev = __shfl_up(to, 1, 64);   // tgt[2i-1]
    const bool skip1 = (lane > 0) && (te != tprev); // l=4i+1: ext[l]!=ext[l-2]
    const bool skip3 = (to != te);                  // l=4i+3
    // even l: blank -> skip always false -> alpha[l-2] never needed there

    const float* base = lp + (size_t)n * CC;        // + t*NN*CC per step
    const long long stride = (long long)NN * CC;

    // D-deep register prefetch pipeline (statically indexed, fully unrolled)
    constexpr int D = 8;
    float rb[D], r1[D], r2[D];
    #pragma unroll
    for (int d = 0; d < D; ++d) {
        const float* p = base + (long long)d * stride;
        rb[d] = p[0];  r1[d] = p[te];  r2[d] = p[to];
    }

    // pre-state: running one normal step from this produces the exact alpha0
    float a0 = (lane == 0) ? 0.0f : NEG;
    float a1 = NEG, a2 = NEG, a3 = NEG, a4 = NEG;

    for (int t0 = 0; t0 < ilen; t0 += D) {
        #pragma unroll
        for (int d = 0; d < D; ++d) {
            const int t = t0 + d;
            if (t >= ilen) break;              // uniform; freeze == stop
            const float eb = rb[d] * LOG2E;    // blank emit (log2 domain)
            const float e1 = r1[d] * LOG2E;
            const float e3 = r2[d] * LOG2E;
            const int tn = t + D;
            if (tn < ilen) {                   // prefetch t+D into slot d
                const float* p = base + (long long)tn * stride;
                rb[d] = p[0];  r1[d] = p[te];  r2[d] = p[to];
            }
            const float s3 = __shfl_up(a3, 1, 64);
            const float p3 = (lane == 0) ? NEG : s3;   // alpha[4i-1]
            const float n0 = eb + lae2(a0, p3);
            const float n1 = e1 + lae3(a1, a0, skip1 ? p3 : NEG);
            const float n2 = eb + lae2(a2, a1);
            const float n3 = e3 + lae3(a3, a2, skip3 ? a1 : NEG);
            const float n4 = eb + lae2(a4, a3);        // l=256 (lane 63 only)
            a0 = n0; a1 = n1; a2 = n2; a3 = n3; a4 = n4;
        }
    }

    // final: loss = -logaddexp(alpha[2*tl], alpha[2*tl-1]) / tl
    __shared__ float alds[260];
    alds[4 * lane + 0] = a0;
    alds[4 * lane + 1] = a1;
    alds[4 * lane + 2] = a2;
    alds[4 * lane + 3] = a3;
    if (lane == 63) alds[256] = a4;
    __syncthreads();
    if (lane == 0) {
        const int idx = 2 * tlen;
        const float r = lae2(alds[idx], alds[idx - 1]);  // log2 domain
        ws[n] = -(r * LN2) / (float)tlen;                // back to ln, /tl
    }
}

__global__ __launch_bounds__(64) void ctc_reduce_kernel(
    const float* __restrict__ ws, float* __restrict__ out)
{
    const int lane = threadIdx.x;
    float s = ws[lane] + ws[lane + 64] + ws[lane + 128] + ws[lane + 192];
    #pragma unroll
    for (int off = 32; off > 0; off >>= 1)
        s += __shfl_down(s, off, 64);
    if (lane == 0) out[0] = s * (1.0f / NN);
}

extern "C" void kernel_launch(void* const* d_in, const int* in_sizes, int n_in,
                              void* d_out, int out_size, void* d_ws, size_t ws_size,
                              hipStream_t stream) {
    const float* lp  = (const float*)d_in[0];   // (T, N, C) f32
    const int*   tgt = (const int*)d_in[1];     // (N, S) i32
    const int*   il  = (const int*)d_in[2];     // (N,) i32
    const int*   tl  = (const int*)d_in[3];     // (N,) i32
    float* out = (float*)d_out;
    float* ws  = (float*)d_ws;

    hipLaunchKernelGGL(ctc_alpha_kernel, dim3(NN), dim3(64), 0, stream,
                       lp, tgt, il, tl, ws);
    hipLaunchKernelGGL(ctc_reduce_kernel, dim3(1), dim3(64), 0, stream, ws, out);
}

// Round 2
// 341.948 us; speedup vs baseline: 2.2870x; 2.2870x over previous
//
#include <hip/hip_runtime.h>

#define TT 1024
#define NN 256
#define CC 128
#define SS 128
#define NEG (-1e30f)
#define LOG2E 1.4426950408889634f
#define LN2 0.6931471805599453f

// log-sum-exp in log2 domain, 2-arg: log2(2^a + 2^b)
__device__ __forceinline__ float lae2(float a, float b) {
    float m = fmaxf(a, b);
    float mn = fminf(a, b);
    float s = 1.0f + __builtin_amdgcn_exp2f(mn - m);
    return m + __builtin_amdgcn_logf(s);   // v_log_f32 is log2
}
// 3-arg: log2(2^a + 2^b + 2^c)
__device__ __forceinline__ float lae3(float a, float b, float c) {
    float m = fmaxf(fmaxf(a, b), c);       // fuses to v_max3_f32
    float s = __builtin_amdgcn_exp2f(a - m) + __builtin_amdgcn_exp2f(b - m)
            + __builtin_amdgcn_exp2f(c - m);
    return m + __builtin_amdgcn_logf(s);
}

// One wave (64 lanes) per batch sample. Lane i owns extended positions
// l = 4i .. 4i+3 (a0..a3); lane 63 additionally owns l=256 (a4).
// Cross-lane dep per step: only alpha[4i-1] = prev lane's a3 (one shfl_up).
//
// CRITICAL (round-1 lesson): the inner D-block must have NO break / no
// lane-divergent control flow, so rb/r1/r2 stay statically indexed and live
// in VGPRs. A `break` inside the unroll forced them to scratch (VGPR=24,
// WRITE_SIZE=9MB, 1495 cy/step).
__global__ __launch_bounds__(64, 1) void ctc_alpha_kernel(
    const float* __restrict__ lp, const int* __restrict__ tgt,
    const int* __restrict__ ilen_p, const int* __restrict__ tlen_p,
    float* __restrict__ ws)
{
    const int n = blockIdx.x;
    const int lane = threadIdx.x;
    const int ilen = ilen_p[n];
    const int tlen = tlen_p[n];

    // time-invariant gather indices: ext[4i+1]=tgt[2i], ext[4i+3]=tgt[2i+1]
    const int te = tgt[n * SS + 2 * lane]     & (CC - 1);
    const int to = tgt[n * SS + 2 * lane + 1] & (CC - 1);
    const int tprev = __shfl_up(to, 1, 64);   // tgt[2i-1]
    const bool skip1 = (lane > 0) && (te != tprev); // l=4i+1: ext[l]!=ext[l-2]
    const bool skip3 = (to != te);                  // l=4i+3

    const float* base = lp + (size_t)n * CC;        // + t*NN*CC per step
    const long long stride = (long long)NN * CC;

    // D-deep register prefetch pipeline (statically indexed, fully unrolled)
    constexpr int D = 16;
    float rb[D], r1[D], r2[D];
    #pragma unroll
    for (int d = 0; d < D; ++d) {
        const float* p = base + (long long)d * stride;
        rb[d] = p[0];  r1[d] = p[te];  r2[d] = p[to];
    }

    // pre-state: running one normal step from this produces the exact alpha0
    float a0 = (lane == 0) ? 0.0f : NEG;
    float a1 = NEG, a2 = NEG, a3 = NEG, a4 = NEG;

    int t0 = 0;
    for (; t0 + D <= ilen; t0 += D) {
        #pragma unroll
        for (int d = 0; d < D; ++d) {
            const int t = t0 + d;
            const float eb = rb[d] * LOG2E;    // blank emit (log2 domain)
            const float e1 = r1[d] * LOG2E;
            const float e3 = r2[d] * LOG2E;
            // branchless prefetch of t+D into slot d (clamped address; slots
            // with tn >= ilen are loaded but never consumed)
            int tn = t + D; tn = (tn < TT) ? tn : (TT - 1);
            const float* p = base + (long long)tn * stride;
            rb[d] = p[0];  r1[d] = p[te];  r2[d] = p[to];

            const float s3 = __shfl_up(a3, 1, 64);
            const float p3 = (lane == 0) ? NEG : s3;   // alpha[4i-1]
            const float n0 = eb + lae2(a0, p3);
            const float n1 = e1 + lae3(a1, a0, skip1 ? p3 : NEG);
            const float n2 = eb + lae2(a2, a1);
            const float n3 = e3 + lae3(a3, a2, skip3 ? a1 : NEG);
            const float n4 = eb + lae2(a4, a3);        // l=256 (lane 63 only)
            a0 = n0; a1 = n1; a2 = n2; a3 = n3; a4 = n4;
        }
    }
    // tail: at most D-1 steps; slots d were prefetched with t = t0 + d by the
    // final main-loop iteration. Uniform scalar `if`s, static indices.
    #pragma unroll
    for (int d = 0; d < D; ++d) {
        if (t0 + d < ilen) {
            const float eb = rb[d] * LOG2E;
            const float e1 = r1[d] * LOG2E;
            const float e3 = r2[d] * LOG2E;
            const float s3 = __shfl_up(a3, 1, 64);
            const float p3 = (lane == 0) ? NEG : s3;
            const float n0 = eb + lae2(a0, p3);
            const float n1 = e1 + lae3(a1, a0, skip1 ? p3 : NEG);
            const float n2 = eb + lae2(a2, a1);
            const float n3 = e3 + lae3(a3, a2, skip3 ? a1 : NEG);
            const float n4 = eb + lae2(a4, a3);
            a0 = n0; a1 = n1; a2 = n2; a3 = n3; a4 = n4;
        }
    }

    // final: loss = -logaddexp(alpha[2*tl], alpha[2*tl-1]) / tl
    __shared__ float alds[260];
    alds[4 * lane + 0] = a0;
    alds[4 * lane + 1] = a1;
    alds[4 * lane + 2] = a2;
    alds[4 * lane + 3] = a3;
    if (lane == 63) alds[256] = a4;
    __syncthreads();
    if (lane == 0) {
        const int idx = 2 * tlen;
        const float r = lae2(alds[idx], alds[idx - 1]);  // log2 domain
        ws[n] = -(r * LN2) / (float)tlen;                // back to ln, /tl
    }
}

__global__ __launch_bounds__(64) void ctc_reduce_kernel(
    const float* __restrict__ ws, float* __restrict__ out)
{
    const int lane = threadIdx.x;
    float s = ws[lane] + ws[lane + 64] + ws[lane + 128] + ws[lane + 192];
    #pragma unroll
    for (int off = 32; off > 0; off >>= 1)
        s += __shfl_down(s, off, 64);
    if (lane == 0) out[0] = s * (1.0f / NN);
}

extern "C" void kernel_launch(void* const* d_in, const int* in_sizes, int n_in,
                              void* d_out, int out_size, void* d_ws, size_t ws_size,
                              hipStream_t stream) {
    const float* lp  = (const float*)d_in[0];   // (T, N, C) f32
    const int*   tgt = (const int*)d_in[1];     // (N, S) i32
    const int*   il  = (const int*)d_in[2];     // (N,) i32
    const int*   tl  = (const int*)d_in[3];     // (N,) i32
    float* out = (float*)d_out;
    float* ws  = (float*)d_ws;

    hipLaunchKernelGGL(ctc_alpha_kernel, dim3(NN), dim3(64), 0, stream,
                       lp, tgt, il, tl, ws);
    hipLaunchKernelGGL(ctc_reduce_kernel, dim3(1), dim3(64), 0, stream, ws, out);
}